// Round 5
// baseline (2987.266 us; speedup 1.0000x reference)
//
#include <hip/hip_runtime.h>
#include <math.h>

// Problem constants (reference: B,P,NTIME,NLATENT,NSPATIAL = 4,2,16,32,2048)
#define NB 4
#define NP 2
#define NT 16
#define NC 32
#define NX 2048

// ---------------------------------------------------------------------------
// Precompute G[c,e,A,B] = sum_{t,T} enc[e,t,T] * K[t,A,c] * V[T,B,c]
// For layer 1 (cstride==1) there is no c axis: G[e,A,B].
// ---------------------------------------------------------------------------
__global__ void g_precompute(const float* __restrict__ K,
                             const float* __restrict__ V,
                             const float* __restrict__ enc,
                             float* __restrict__ G,
                             int cstride) {
    const int bid = blockIdx.x;
    int e, c;
    if (cstride == 1) { e = bid; c = 0; }
    else              { c = bid >> 4; e = bid & 15; }

    __shared__ float sK[256], sV[256], sE[256], sW[256];
    const int tid = threadIdx.x;
    {
        const int t = tid >> 4, A = tid & 15;
        sK[tid] = K[(t * 16 + A) * cstride + c];
        sV[tid] = V[(t * 16 + A) * cstride + c];
        sE[tid] = enc[(e * 16 + t) * 16 + A];
    }
    __syncthreads();
    {   // W[t,B] = sum_T enc[e,t,T] * V[T,B,c]
        const int t = tid >> 4, Bi = tid & 15;
        float acc = 0.f;
#pragma unroll
        for (int T = 0; T < 16; ++T) acc += sE[t * 16 + T] * sV[T * 16 + Bi];
        sW[tid] = acc;
    }
    __syncthreads();
    {   // G[A,B] = sum_t K[t,A,c] * W[t,B]
        const int A = tid >> 4, Bi = tid & 15;
        float acc = 0.f;
#pragma unroll
        for (int t = 0; t < 16; ++t) acc += sK[t * 16 + A] * sW[t * 16 + Bi];
        G[((c * 16 + e) * 16 + A) * 16 + Bi] = acc;
    }
}

// M1t[e][E][T] = sum_t Q1[t,T] * dec[e,t,E]   (q1 fused; laid out for per-e rows)
__global__ void m1t_precompute(const float* __restrict__ Q1,
                               const float* __restrict__ dec,
                               float* __restrict__ M1t) {
    const int idx = blockIdx.x * 256 + threadIdx.x;  // 4096
    const int e = idx >> 8, E = (idx >> 4) & 15, T = idx & 15;
    float acc = 0.f;
#pragma unroll
    for (int t = 0; t < 16; ++t)
        acc += Q1[t * 16 + T] * dec[(e * 16 + t) * 16 + E];
    M1t[idx] = acc;
}

// M2[c][T][A][E] = sum_t Q0[t,A,c] * dec[E,t,T]  (q0 fused into final stage)
__global__ void m2_precompute(const float* __restrict__ Q0,
                              const float* __restrict__ dec,
                              float* __restrict__ M2) {
    const int idx = blockIdx.x * 256 + threadIdx.x;  // 131072
    const int c = idx >> 12, T = (idx >> 8) & 15, A = (idx >> 4) & 15, E = idx & 15;
    float acc = 0.f;
#pragma unroll
    for (int t = 0; t < 16; ++t)
        acc += Q0[(t * 16 + A) * NC + c] * dec[(E * 16 + t) * 16 + T];
    M2[idx] = acc;
}

__device__ __forceinline__ float sqrt_act(float v) {
    return copysignf(sqrtf(fabsf(v)), v);
}

// dot of one 16-float LDS weight row (wave-uniform broadcast) against TWO
// per-thread 16-vectors. 4 independent FMA chains.
__device__ __forceinline__ void dot2(const float* __restrict__ row,
                                     const float (&v0)[16], const float (&v1)[16],
                                     float& s0, float& s1) {
    float a0 = 0.f, b0 = 0.f, a1 = 0.f, b1 = 0.f;
#pragma unroll
    for (int i = 0; i < 16; i += 2) {
        a0 += row[i] * v0[i];     b0 += row[i + 1] * v0[i + 1];
        a1 += row[i] * v1[i];     b1 += row[i + 1] * v1[i + 1];
    }
    s0 = a0 + b0;
    s1 = a1 + b1;
}

// ---------------------------------------------------------------------------
// Main kernel: one thread per TWO (b,p,c,x) sites (x and x+256).
// Weights staged in LDS, read as wave-uniform broadcast ds_read_b128.
// Stages 1+2 fused (p_e consumed immediately) to keep peak live regs < 128.
// __launch_bounds__(256,4): VGPR<=128 -> 4 blocks/CU -> 16 waves/CU.
// grid = NB*NP*NC*(NX/512) = 1024 blocks = exactly 4 per CU.
// ---------------------------------------------------------------------------
__global__ __launch_bounds__(256, 4) void site_kernel(
    const float* __restrict__ x,
    const float* __restrict__ a,
    const float* __restrict__ w,
    const float* __restrict__ G0,
    const float* __restrict__ G1,
    const float* __restrict__ M1t,
    const float* __restrict__ M2,
    float* __restrict__ out) {
    const int tid = threadIdx.x;
    const int bid = blockIdx.x;
    const int xc = bid & 3;
    const int c  = (bid >> 2) & 31;
    const int bp = bid >> 7;              // [0, NB*NP)
    const int x0 = (xc << 9) + tid;       // column of site 0; site 1 = x0+256
    const float* xb = x + (bp * NT * NC + c) * NX;

    __shared__ float sw[8192];            // up to 32 KB of staged weights

    // cooperative fill of N4 float4's at sw-offset OFS (in floats)
#define FILL(SRC, OFS, N4)                                                \
    do {                                                                  \
        const float4* s4 = (const float4*)(SRC);                          \
        float4* d4 = (float4*)(sw + (OFS));                               \
        _Pragma("unroll")                                                 \
        for (int i = 0; i < (N4); ++i) d4[tid + 256 * i] = s4[tid + 256 * i];\
    } while (0)

    // ---- load both sites' 16-vectors (coalesced) ----
    float X0[16], X1[16];
#pragma unroll
    for (int t = 0; t < 16; ++t) {
        X0[t] = xb[t * NC * NX + x0];
        X1[t] = xb[t * NC * NX + x0 + 256];
    }

    // ======== stage 0: h[e] = sqrt_act( X^T G0[c,e] X ) ========
    FILL(G0 + c * 4096, 0, 4);
    __syncthreads();
    float h0[16], h1[16];
    {
#pragma unroll 1
        for (int e = 0; e < 16; ++e) {
            const float* g = sw + e * 256;
            float A0 = 0.f, B0 = 0.f, A1 = 0.f, B1 = 0.f;
#pragma unroll
            for (int A = 0; A < 16; ++A) {
                float s0, s1;
                dot2(g + A * 16, X0, X1, s0, s1);
                if (A & 1) { B0 += X0[A] * s0; B1 += X1[A] * s1; }
                else       { A0 += X0[A] * s0; A1 += X1[A] * s1; }
            }
            h0[e] = sqrt_act(A0 + B0);
            h1[e] = sqrt_act(A1 + B1);
        }
    }
    // X0/X1 dead here (re-loaded for the final stage).

    // ======== stages 1+2 fused:
    //   p_e = a[e,x] * sqrt_act( h^T G1[e] h )
    //   b2[E] += p_e * ( sum_T h_T * M1t[e,E,T] )      (p never materialized)
    __syncthreads();
    FILL(G1, 0, 4);
    FILL(M1t, 4096, 4);
    __syncthreads();
    float b20[16], b21[16];
#pragma unroll
    for (int E = 0; E < 16; ++E) { b20[E] = 0.f; b21[E] = 0.f; }
    {
#pragma unroll 1
        for (int e = 0; e < 16; ++e) {
            const float ae0 = a[e * NX + x0];
            const float ae1 = a[e * NX + x0 + 256];
            const float* g = sw + e * 256;
            float A0 = 0.f, B0 = 0.f, A1 = 0.f, B1 = 0.f;
#pragma unroll
            for (int A = 0; A < 16; ++A) {
                float s0, s1;
                dot2(g + A * 16, h0, h1, s0, s1);
                if (A & 1) { B0 += h0[A] * s0; B1 += h1[A] * s1; }
                else       { A0 += h0[A] * s0; A1 += h1[A] * s1; }
            }
            const float pe0 = ae0 * sqrt_act(A0 + B0);
            const float pe1 = ae1 * sqrt_act(A1 + B1);
            const float* m = sw + 4096 + e * 256;
#pragma unroll
            for (int E = 0; E < 16; ++E) {
                float s0, s1;
                dot2(m + E * 16, h0, h1, s0, s1);
                b20[E] += pe0 * s0;
                b21[E] += pe1 * s1;
            }
        }
    }
    // h dead here.

    // ---- re-load X behind an opaque barrier (prevents CSE keeping X alive) ----
    const float* xr = xb;
    asm volatile("" : "+r"(xr));
    float Y0[16], Y1[16];
#pragma unroll
    for (int t = 0; t < 16; ++t) {
        Y0[t] = xr[t * NC * NX + x0];
        Y1[t] = xr[t * NC * NX + x0 + 256];
    }

    // ======== stage 3: y = sum_T w[T,x] * ( Y^T M2[c,T] b2 ) ========
    __syncthreads();
    FILL(M2 + c * 4096, 0, 4);
    __syncthreads();
    float y0 = 0.f, y1 = 0.f;
    {
#pragma unroll 1
        for (int T = 0; T < 16; ++T) {
            const float wt0 = w[T * NX + x0];
            const float wt1 = w[T * NX + x0 + 256];
            const float* m = sw + T * 256;
            float A0 = 0.f, B0 = 0.f, A1 = 0.f, B1 = 0.f;
#pragma unroll
            for (int A = 0; A < 16; ++A) {
                float s0, s1;
                dot2(m + A * 16, b20, b21, s0, s1);
                if (A & 1) { B0 += Y0[A] * s0; B1 += Y1[A] * s1; }
                else       { A0 += Y0[A] * s0; A1 += Y1[A] * s1; }
            }
            y0 += wt0 * (A0 + B0);
            y1 += wt1 * (A1 + B1);
        }
    }
#undef FILL

    // ---- reduce over the block, one atomic per block ----
    float y = y0 + y1;
#pragma unroll
    for (int off = 32; off > 0; off >>= 1) y += __shfl_down(y, off);
    __shared__ float red[4];
    if ((tid & 63) == 0) red[tid >> 6] = y;
    __syncthreads();
    if (tid == 0) {
        atomicAdd(&out[bp * NC + c], red[0] + red[1] + red[2] + red[3]);
    }
}

extern "C" void kernel_launch(void* const* d_in, const int* in_sizes, int n_in,
                              void* d_out, int out_size, void* d_ws, size_t ws_size,
                              hipStream_t stream) {
    const float* x   = (const float*)d_in[0];
    const float* K0  = (const float*)d_in[1];
    const float* Q0  = (const float*)d_in[2];
    const float* V0  = (const float*)d_in[3];
    const float* K1  = (const float*)d_in[4];
    const float* Q1  = (const float*)d_in[5];
    const float* V1  = (const float*)d_in[6];
    const float* enc = (const float*)d_in[7];
    const float* dec = (const float*)d_in[8];
    const float* a   = (const float*)d_in[9];
    const float* w   = (const float*)d_in[10];
    float* out = (float*)d_out;

    float* G0  = (float*)d_ws;       // 32*4096 = 131072 floats
    float* G1  = G0 + NC * 4096;     // 4096
    float* M1t = G1 + 4096;          // 4096
    float* M2  = M1t + 4096;         // 131072
    // total ws: 270336 floats ~= 1.06 MB

    // out must be zeroed every call (harness re-poisons with 0xAA)
    hipMemsetAsync(d_out, 0, (size_t)out_size * sizeof(float), stream);

    g_precompute<<<NC * 16, 256, 0, stream>>>(K0, V0, enc, G0, NC);
    g_precompute<<<16,      256, 0, stream>>>(K1, V1, enc, G1, 1);
    m1t_precompute<<<16,  256, 0, stream>>>(Q1, dec, M1t);
    m2_precompute<<<512, 256, 0, stream>>>(Q0, dec, M2);

    const int nblocks = NB * NP * NC * (NX / 512);  // 1024
    site_kernel<<<nblocks, 256, 0, stream>>>(x, a, w, G0, G1, M1t, M2, out);
}

// Round 6
// 485.435 us; speedup vs baseline: 6.1538x; 6.1538x over previous
//
#include <hip/hip_runtime.h>
#include <math.h>

// Problem constants (reference: B,P,NTIME,NLATENT,NSPATIAL = 4,2,16,32,2048)
#define NB 4
#define NP 2
#define NT 16
#define NC 32
#define NX 2048

// ---------------------------------------------------------------------------
// Precompute G[c,e,A,B] = sum_{t,T} enc[e,t,T] * K[t,A,c] * V[T,B,c]
// For layer 1 (cstride==1) there is no c axis: G[e,A,B].
// ---------------------------------------------------------------------------
__global__ void g_precompute(const float* __restrict__ K,
                             const float* __restrict__ V,
                             const float* __restrict__ enc,
                             float* __restrict__ G,
                             int cstride) {
    const int bid = blockIdx.x;
    int e, c;
    if (cstride == 1) { e = bid; c = 0; }
    else              { c = bid >> 4; e = bid & 15; }

    __shared__ float sK[256], sV[256], sE[256], sW[256];
    const int tid = threadIdx.x;
    {
        const int t = tid >> 4, A = tid & 15;
        sK[tid] = K[(t * 16 + A) * cstride + c];
        sV[tid] = V[(t * 16 + A) * cstride + c];
        sE[tid] = enc[(e * 16 + t) * 16 + A];
    }
    __syncthreads();
    {   // W[t,B] = sum_T enc[e,t,T] * V[T,B,c]
        const int t = tid >> 4, Bi = tid & 15;
        float acc = 0.f;
#pragma unroll
        for (int T = 0; T < 16; ++T) acc += sE[t * 16 + T] * sV[T * 16 + Bi];
        sW[tid] = acc;
    }
    __syncthreads();
    {   // G[A,B] = sum_t K[t,A,c] * W[t,B]
        const int A = tid >> 4, Bi = tid & 15;
        float acc = 0.f;
#pragma unroll
        for (int t = 0; t < 16; ++t) acc += sK[t * 16 + A] * sW[t * 16 + Bi];
        G[((c * 16 + e) * 16 + A) * 16 + Bi] = acc;
    }
}

// M1t[e][E][T] = sum_t Q1[t,T] * dec[e,t,E]   (q1 fused; laid out for per-e rows)
__global__ void m1t_precompute(const float* __restrict__ Q1,
                               const float* __restrict__ dec,
                               float* __restrict__ M1t) {
    const int idx = blockIdx.x * 256 + threadIdx.x;  // 4096
    const int e = idx >> 8, E = (idx >> 4) & 15, T = idx & 15;
    float acc = 0.f;
#pragma unroll
    for (int t = 0; t < 16; ++t)
        acc += Q1[t * 16 + T] * dec[(e * 16 + t) * 16 + E];
    M1t[idx] = acc;
}

// M2[c][T][A][E] = sum_t Q0[t,A,c] * dec[E,t,T]  (q0 fused into final stage)
__global__ void m2_precompute(const float* __restrict__ Q0,
                              const float* __restrict__ dec,
                              float* __restrict__ M2) {
    const int idx = blockIdx.x * 256 + threadIdx.x;  // 131072
    const int c = idx >> 12, T = (idx >> 8) & 15, A = (idx >> 4) & 15, E = idx & 15;
    float acc = 0.f;
#pragma unroll
    for (int t = 0; t < 16; ++t)
        acc += Q0[(t * 16 + A) * NC + c] * dec[(E * 16 + t) * 16 + T];
    M2[idx] = acc;
}

__device__ __forceinline__ float sqrt_act(float v) {
    return copysignf(sqrtf(fabsf(v)), v);
}

// dot of one 16-float LDS weight row (wave-uniform) against FOUR per-thread
// 16-vectors. 8 independent FMA chains; amortizes the LDS datapath cost of
// the row over 4 sites (the binding resource per the R4/R5 post-mortem).
__device__ __forceinline__ void dot4(const float* __restrict__ row,
                                     const float (&v0)[16], const float (&v1)[16],
                                     const float (&v2)[16], const float (&v3)[16],
                                     float& s0, float& s1, float& s2, float& s3) {
    float a0 = 0.f, b0 = 0.f, a1 = 0.f, b1 = 0.f;
    float a2 = 0.f, b2 = 0.f, a3 = 0.f, b3 = 0.f;
#pragma unroll
    for (int i = 0; i < 16; i += 2) {
        a0 += row[i] * v0[i];     b0 += row[i + 1] * v0[i + 1];
        a1 += row[i] * v1[i];     b1 += row[i + 1] * v1[i + 1];
        a2 += row[i] * v2[i];     b2 += row[i + 1] * v2[i + 1];
        a3 += row[i] * v3[i];     b3 += row[i + 1] * v3[i + 1];
    }
    s0 = a0 + b0;  s1 = a1 + b1;  s2 = a2 + b2;  s3 = a3 + b3;
}

// ---------------------------------------------------------------------------
// Main kernel: one thread per FOUR (b,p,c,x) sites (x0 + {0,256,512,768}).
// Weights staged in LDS (read wave-uniform); R=4 halves LDS datapath time
// vs R=2 (164 us model floor) while FMA floor is 119 us.
// Stages 1+2 fused (p_e consumed immediately; live set = h + b2 only).
// NO min-waves launch bound (R5 lesson: a hard VGPR cap => catastrophic spill).
// grid = NB*NP*NC*(NX/1024) = 512 blocks of 256 threads = exactly 2/CU.
// bid bits: [0]=x-chunk, [5:1]=c, [8:6]=bp
// ---------------------------------------------------------------------------
__global__ __launch_bounds__(256) void site_kernel(
    const float* __restrict__ x,
    const float* __restrict__ a,
    const float* __restrict__ w,
    const float* __restrict__ G0,
    const float* __restrict__ G1,
    const float* __restrict__ M1t,
    const float* __restrict__ M2,
    float* __restrict__ out) {
    const int tid = threadIdx.x;
    const int bid = blockIdx.x;
    const int xc = bid & 1;
    const int c  = (bid >> 1) & 31;
    const int bp = bid >> 6;              // [0, NB*NP)
    const int x0 = (xc << 10) + tid;      // site s at x0 + s*256
    const float* xb = x + (bp * NT * NC + c) * NX;

    __shared__ float sw[8192];            // up to 32 KB of staged weights

    // cooperative fill of N4 float4's at sw-offset OFS (in floats)
#define FILL(SRC, OFS, N4)                                                \
    do {                                                                  \
        const float4* s4 = (const float4*)(SRC);                          \
        float4* d4 = (float4*)(sw + (OFS));                               \
        _Pragma("unroll")                                                 \
        for (int i = 0; i < (N4); ++i) d4[tid + 256 * i] = s4[tid + 256 * i];\
    } while (0)

    // ---- load all four sites' 16-vectors (coalesced) ----
    float X0[16], X1[16], X2[16], X3[16];
#pragma unroll
    for (int t = 0; t < 16; ++t) {
        X0[t] = xb[t * NC * NX + x0];
        X1[t] = xb[t * NC * NX + x0 + 256];
        X2[t] = xb[t * NC * NX + x0 + 512];
        X3[t] = xb[t * NC * NX + x0 + 768];
    }

    // ======== stage 0: h[e] = sqrt_act( X^T G0[c,e] X ) ========
    FILL(G0 + c * 4096, 0, 4);
    __syncthreads();
    float h0[16], h1[16], h2[16], h3[16];
    {
#pragma unroll 1
        for (int e = 0; e < 16; ++e) {
            const float* g = sw + e * 256;
            float c0 = 0.f, d0 = 0.f, c1 = 0.f, d1 = 0.f;
            float c2 = 0.f, d2 = 0.f, c3 = 0.f, d3 = 0.f;
#pragma unroll
            for (int A = 0; A < 16; ++A) {
                float s0, s1, s2, s3;
                dot4(g + A * 16, X0, X1, X2, X3, s0, s1, s2, s3);
                if (A & 1) { d0 += X0[A] * s0; d1 += X1[A] * s1;
                             d2 += X2[A] * s2; d3 += X3[A] * s3; }
                else       { c0 += X0[A] * s0; c1 += X1[A] * s1;
                             c2 += X2[A] * s2; c3 += X3[A] * s3; }
            }
            h0[e] = sqrt_act(c0 + d0);
            h1[e] = sqrt_act(c1 + d1);
            h2[e] = sqrt_act(c2 + d2);
            h3[e] = sqrt_act(c3 + d3);
        }
    }
    // X dead here (re-loaded for the final stage).

    // ======== stages 1+2 fused:
    //   p_e = a[e,x] * sqrt_act( h^T G1[e] h )
    //   b2[E] += p_e * ( sum_T h_T * M1t[e,E,T] )      (p never materialized)
    __syncthreads();
    FILL(G1, 0, 4);
    FILL(M1t, 4096, 4);
    __syncthreads();
    float b20[16], b21[16], b22[16], b23[16];
#pragma unroll
    for (int E = 0; E < 16; ++E) { b20[E] = 0.f; b21[E] = 0.f;
                                   b22[E] = 0.f; b23[E] = 0.f; }
    {
#pragma unroll 1
        for (int e = 0; e < 16; ++e) {
            const float ae0 = a[e * NX + x0];
            const float ae1 = a[e * NX + x0 + 256];
            const float ae2 = a[e * NX + x0 + 512];
            const float ae3 = a[e * NX + x0 + 768];
            const float* g = sw + e * 256;
            float c0 = 0.f, d0 = 0.f, c1 = 0.f, d1 = 0.f;
            float c2 = 0.f, d2 = 0.f, c3 = 0.f, d3 = 0.f;
#pragma unroll
            for (int A = 0; A < 16; ++A) {
                float s0, s1, s2, s3;
                dot4(g + A * 16, h0, h1, h2, h3, s0, s1, s2, s3);
                if (A & 1) { d0 += h0[A] * s0; d1 += h1[A] * s1;
                             d2 += h2[A] * s2; d3 += h3[A] * s3; }
                else       { c0 += h0[A] * s0; c1 += h1[A] * s1;
                             c2 += h2[A] * s2; c3 += h3[A] * s3; }
            }
            const float pe0 = ae0 * sqrt_act(c0 + d0);
            const float pe1 = ae1 * sqrt_act(c1 + d1);
            const float pe2 = ae2 * sqrt_act(c2 + d2);
            const float pe3 = ae3 * sqrt_act(c3 + d3);
            const float* m = sw + 4096 + e * 256;
#pragma unroll
            for (int E = 0; E < 16; ++E) {
                float s0, s1, s2, s3;
                dot4(m + E * 16, h0, h1, h2, h3, s0, s1, s2, s3);
                b20[E] += pe0 * s0;
                b21[E] += pe1 * s1;
                b22[E] += pe2 * s2;
                b23[E] += pe3 * s3;
            }
        }
    }
    // h dead here.

    // ---- re-load X behind an opaque barrier (prevents CSE keeping X alive) ----
    const float* xr = xb;
    asm volatile("" : "+r"(xr));
    float Y0[16], Y1[16], Y2[16], Y3[16];
#pragma unroll
    for (int t = 0; t < 16; ++t) {
        Y0[t] = xr[t * NC * NX + x0];
        Y1[t] = xr[t * NC * NX + x0 + 256];
        Y2[t] = xr[t * NC * NX + x0 + 512];
        Y3[t] = xr[t * NC * NX + x0 + 768];
    }

    // ======== stage 3: y = sum_T w[T,x] * ( Y^T M2[c,T] b2 ) ========
    __syncthreads();
    FILL(M2 + c * 4096, 0, 4);
    __syncthreads();
    float y0 = 0.f, y1 = 0.f, y2 = 0.f, y3 = 0.f;
    {
#pragma unroll 1
        for (int T = 0; T < 16; ++T) {
            const float wt0 = w[T * NX + x0];
            const float wt1 = w[T * NX + x0 + 256];
            const float wt2 = w[T * NX + x0 + 512];
            const float wt3 = w[T * NX + x0 + 768];
            const float* m = sw + T * 256;
            float c0 = 0.f, d0 = 0.f, c1 = 0.f, d1 = 0.f;
            float c2 = 0.f, d2 = 0.f, c3 = 0.f, d3 = 0.f;
#pragma unroll
            for (int A = 0; A < 16; ++A) {
                float s0, s1, s2, s3;
                dot4(m + A * 16, b20, b21, b22, b23, s0, s1, s2, s3);
                if (A & 1) { d0 += Y0[A] * s0; d1 += Y1[A] * s1;
                             d2 += Y2[A] * s2; d3 += Y3[A] * s3; }
                else       { c0 += Y0[A] * s0; c1 += Y1[A] * s1;
                             c2 += Y2[A] * s2; c3 += Y3[A] * s3; }
            }
            y0 += wt0 * (c0 + d0);
            y1 += wt1 * (c1 + d1);
            y2 += wt2 * (c2 + d2);
            y3 += wt3 * (c3 + d3);
        }
    }
#undef FILL

    // ---- reduce over the block, one atomic per block ----
    float y = (y0 + y1) + (y2 + y3);
#pragma unroll
    for (int off = 32; off > 0; off >>= 1) y += __shfl_down(y, off);
    __shared__ float red[4];
    if ((tid & 63) == 0) red[tid >> 6] = y;
    __syncthreads();
    if (tid == 0) {
        atomicAdd(&out[bp * NC + c], red[0] + red[1] + red[2] + red[3]);
    }
}

extern "C" void kernel_launch(void* const* d_in, const int* in_sizes, int n_in,
                              void* d_out, int out_size, void* d_ws, size_t ws_size,
                              hipStream_t stream) {
    const float* x   = (const float*)d_in[0];
    const float* K0  = (const float*)d_in[1];
    const float* Q0  = (const float*)d_in[2];
    const float* V0  = (const float*)d_in[3];
    const float* K1  = (const float*)d_in[4];
    const float* Q1  = (const float*)d_in[5];
    const float* V1  = (const float*)d_in[6];
    const float* enc = (const float*)d_in[7];
    const float* dec = (const float*)d_in[8];
    const float* a   = (const float*)d_in[9];
    const float* w   = (const float*)d_in[10];
    float* out = (float*)d_out;

    float* G0  = (float*)d_ws;       // 32*4096 = 131072 floats
    float* G1  = G0 + NC * 4096;     // 4096
    float* M1t = G1 + 4096;          // 4096
    float* M2  = M1t + 4096;         // 131072
    // total ws: 270336 floats ~= 1.06 MB

    // out must be zeroed every call (harness re-poisons with 0xAA)
    hipMemsetAsync(d_out, 0, (size_t)out_size * sizeof(float), stream);

    g_precompute<<<NC * 16, 256, 0, stream>>>(K0, V0, enc, G0, NC);
    g_precompute<<<16,      256, 0, stream>>>(K1, V1, enc, G1, 1);
    m1t_precompute<<<16,  256, 0, stream>>>(Q1, dec, M1t);
    m2_precompute<<<512, 256, 0, stream>>>(Q0, dec, M2);

    const int nblocks = NB * NP * NC * (NX / 1024);  // 512
    site_kernel<<<nblocks, 256, 0, stream>>>(x, a, w, G0, G1, M1t, M2, out);
}